// Round 2
// baseline (611.775 us; speedup 1.0000x reference)
//
#include <hip/hip_runtime.h>

#define NQ 2048
#define NK 512
#define DD 128

typedef __bf16 bf16_t;
typedef bf16_t bf16x4 __attribute__((ext_vector_type(4)));
typedef bf16_t bf16x8 __attribute__((ext_vector_type(8)));
typedef float  f32x4  __attribute__((ext_vector_type(4)));

// swizzled index into row-major [row][128] bf16 LDS tile (XOR byte-swizzle, G4/T2)
__device__ __forceinline__ int swz(int row, int d) {
  return row * 128 + (d ^ ((row & 7) << 3));
}

__device__ __forceinline__ float blockSum(float v, volatile float* sRed) {
  #pragma unroll
  for (int m = 32; m; m >>= 1) v += __shfl_xor(v, m);
  __syncthreads();                       // protect sRed from previous use
  if ((threadIdx.x & 63) == 0) sRed[threadIdx.x >> 6] = v;
  __syncthreads();
  return sRed[0] + sRed[1] + sRed[2] + sRed[3];
}

__device__ __forceinline__ float blockMax(float v, volatile float* sRed) {
  #pragma unroll
  for (int m = 32; m; m >>= 1) v = fmaxf(v, __shfl_xor(v, m));
  __syncthreads();
  if ((threadIdx.x & 63) == 0) sRed[threadIdx.x >> 6] = v;
  __syncthreads();
  return fmaxf(fmaxf(sRed[0], sRed[1]), fmaxf(sRed[2], sRed[3]));
}

// ---- prep: W_pr1 (128x128 f32) -> bf16, fragment-ready layout.
// idx = (et*4+kt)*64 + lane ; lane: rr=lane&15, rg=lane>>4
// frag j<4 : W[et*16+rr][kt*32+rg*4 + j]
// frag j>=4: W[et*16+rr][kt*32+rg*4 + 12 + j]
__global__ __launch_bounds__(256) void prep_w(const float* __restrict__ Wp1,
                                              bf16_t* __restrict__ wsW) {
  int idx = blockIdx.x * 256 + threadIdx.x;   // 0..2047
  int et = idx >> 8, kt = (idx >> 6) & 3, lane = idx & 63;
  int rr = lane & 15, rg = lane >> 4;
  int erow = et * 16 + rr;
  int dlo  = kt * 32 + rg * 4;
  bf16x8 v;
  #pragma unroll
  for (int j = 0; j < 4; ++j) v[j]     = (bf16_t)Wp1[erow * 128 + dlo + j];
  #pragma unroll
  for (int j = 0; j < 4; ++j) v[j + 4] = (bf16_t)Wp1[erow * 128 + dlo + 16 + j];
  *(bf16x8*)(&wsW[(size_t)idx * 8]) = v;
}

__global__ __launch_bounds__(256, 5) void fused_np_attn(
    const float* __restrict__ Q,   const float* __restrict__ K,
    const float* __restrict__ V,   const float* __restrict__ eps,
    const float* __restrict__ Wmu, const float* __restrict__ bmu,
    const float* __restrict__ Wlv, const float* __restrict__ blv,
    const bf16_t* __restrict__ wsW, const float* __restrict__ bp1,
    const float* __restrict__ Wp2, const float* __restrict__ bp2,
    const float* __restrict__ gamma, const float* __restrict__ beta,
    float* __restrict__ out, float* __restrict__ klp)
{
  __shared__ __align__(16) bf16_t sK[64 * 128];   // K chunk [key][d] bf16, swizzled (16 KB); aliased as sCtx
  __shared__ float sB1[128], sW2[128], sWm2[128], sWl2[128];
  __shared__ float sKmu[NK], sKlv[NK], sMup[NK], sS[NK];
  __shared__ float sRed[4];

  const int q    = blockIdx.x;
  const int t    = threadIdx.x;
  const int lane = t & 63;
  const int wave = t >> 6;

  // ---- stage small vectors
  if (t < 128) {
    sB1[t]  = bp1[t];
    sW2[t]  = Wp2[t];
    sWm2[t] = Wmu[128 + t];
    sWl2[t] = Wlv[128 + t];
  }
  // ---- qmu, qlv = Q[q] . Wmu[:128], Wlv[:128]
  float pm = 0.f, pl = 0.f;
  if (t < 128) {
    float qv = Q[(size_t)q * 128 + t];
    pm = qv * Wmu[t];
    pl = qv * Wlv[t];
  }
  __syncthreads();   // small vectors ready; then reduce
  const float qmu = blockSum(pm, sRed);
  const float qlv = blockSum(pl, sRed);

  const float b_mu = bmu[0], b_lv = blv[0], b_p2 = bp2[0];

  // ================= chunked K processing =================
  const int rg = lane >> 4;    // 0..3 : k-group
  const int rr = lane & 15;    // 0..15: row-in-tile (A) / col e (B/D)
  const bf16x8* wsW8 = reinterpret_cast<const bf16x8*>(wsW);

  for (int chunk = 0; chunk < 8; ++chunk) {
    // ---- stage 64 keys x 128 d: thread t -> key=t>>2, d-range 32*(t&3)
    {
      int key  = t >> 2;
      int gkey = chunk * 64 + key;
      int d0   = (t & 3) * 32;
      const float* src = K + (((size_t)q * NK + gkey) * 128 + d0);
      float4 f[8];
      #pragma unroll
      for (int i = 0; i < 8; ++i) f[i] = *(const float4*)(src + i * 4);
      float kmu_p = 0.f, klv_p = 0.f;
      #pragma unroll
      for (int i = 0; i < 8; ++i) {
        int b = d0 + i * 4;
        kmu_p += f[i].x * sWm2[b] + f[i].y * sWm2[b + 1] + f[i].z * sWm2[b + 2] + f[i].w * sWm2[b + 3];
        klv_p += f[i].x * sWl2[b] + f[i].y * sWl2[b + 1] + f[i].z * sWl2[b + 2] + f[i].w * sWl2[b + 3];
      }
      #pragma unroll
      for (int i = 0; i < 4; ++i) {
        float4 a = f[2 * i], b2 = f[2 * i + 1];
        bf16x8 v = {(bf16_t)a.x,  (bf16_t)a.y,  (bf16_t)a.z,  (bf16_t)a.w,
                    (bf16_t)b2.x, (bf16_t)b2.y, (bf16_t)b2.z, (bf16_t)b2.w};
        *(bf16x8*)(&sK[swz(key, d0 + i * 8)]) = v;
      }
      kmu_p += __shfl_xor(kmu_p, 1); kmu_p += __shfl_xor(kmu_p, 2);
      klv_p += __shfl_xor(klv_p, 1); klv_p += __shfl_xor(klv_p, 2);
      if ((t & 3) == 0) { sKmu[gkey] = kmu_p; sKlv[gkey] = klv_p; }
    }
    __syncthreads();

    // ---- MFMA: wave handles keys [wave*16, wave*16+16); h = relu(K W1^T + b1); mup = h . W2
    f32x4 acc[8];
    #pragma unroll
    for (int et = 0; et < 8; ++et) acc[et] = 0;

    const int arow = wave * 16 + rr;
    #pragma unroll
    for (int kt = 0; kt < 4; ++kt) {
      int dlo = kt * 32 + rg * 4;
      bf16x4 alo = *(const bf16x4*)(&sK[swz(arow, dlo)]);
      bf16x4 ahi = *(const bf16x4*)(&sK[swz(arow, dlo + 16)]);
      bf16x8 a = {alo[0], alo[1], alo[2], alo[3], ahi[0], ahi[1], ahi[2], ahi[3]};
      #pragma unroll
      for (int et = 0; et < 8; ++et) {
        bf16x8 b = wsW8[(et * 4 + kt) * 64 + lane];   // L1-resident fragment
        acc[et] = __builtin_amdgcn_mfma_f32_16x16x32_bf16(a, b, acc[et], 0, 0, 0);
      }
    }
    // epilogue: relu + dot with W2, reduce over the 16 e-cols held across lanes
    float mup[4] = {0.f, 0.f, 0.f, 0.f};
    #pragma unroll
    for (int et = 0; et < 8; ++et) {
      int e = et * 16 + rr;
      float b1 = sB1[e], w2 = sW2[e];
      #pragma unroll
      for (int r = 0; r < 4; ++r) {
        float h = fmaxf(acc[et][r] + b1, 0.f);
        mup[r] += h * w2;
      }
    }
    #pragma unroll
    for (int r = 0; r < 4; ++r) {
      mup[r] += __shfl_xor(mup[r], 1);
      mup[r] += __shfl_xor(mup[r], 2);
      mup[r] += __shfl_xor(mup[r], 4);
      mup[r] += __shfl_xor(mup[r], 8);
    }
    if (rr == 0) {
      #pragma unroll
      for (int r = 0; r < 4; ++r)
        sMup[chunk * 64 + wave * 16 + rg * 4 + r] = mup[r] + b_p2 - 0.5f;
    }
    __syncthreads();   // sMup done; sK free for next chunk
  }

  // ================= posterior, KL, samples =================
  float klacc = 0.f, smax = -1e30f;
  float sval[2];
  #pragma unroll
  for (int i = 0; i < 2; ++i) {
    int k = t + i * 256;
    float kmu = sKmu[k], klv = sKlv[k], mupr = sMup[k];
    float mu0 = qmu + kmu + b_mu;
    float lv  = qlv + klv + b_lv;
    float sp  = expf(0.5f * lv);
    float sp2 = sp * sp;
    float mu  = mu0 - 0.5f * sp2;
    float dd  = mu - mupr;
    klacc += -0.5f * lv + 0.5f * (sp2 + dd * dd) - 0.5f;
    float s = expf(mu + sp * eps[(size_t)q * NK + k]);
    sval[i] = s;
    smax = fmaxf(smax, s);
  }
  float mx = blockMax(smax, sRed);
  float esum = 0.f, ev[2];
  #pragma unroll
  for (int i = 0; i < 2; ++i) { ev[i] = expf(sval[i] - mx); esum += ev[i]; }
  float tot = blockSum(esum, sRed);
  float inv = 1.f / tot;
  #pragma unroll
  for (int i = 0; i < 2; ++i) sS[t + i * 256] = ev[i] * inv;   // weights
  float klb = blockSum(klacc, sRed);   // also orders sS writes before phase 3
  if (t == 0) klp[q] = klb;

  // ================= context = weights . V, then LayerNorm =================
  float* sCtx = reinterpret_cast<float*>(sK);   // 8 x 128 f32 (sK dead)
  {
    int slot = t >> 5, l16 = t & 31;
    f32x4 acc = 0;
    const float4* V4 = reinterpret_cast<const float4*>(V + (size_t)q * NK * 128);
    for (int key = slot; key < NK; key += 8) {
      float w = sS[key];
      float4 v = V4[key * 32 + l16];
      acc.x += w * v.x; acc.y += w * v.y; acc.z += w * v.z; acc.w += w * v.w;
    }
    *(f32x4*)(&sCtx[slot * 128 + l16 * 4]) = acc;
  }
  __syncthreads();

  float ctx = 0.f, s1 = 0.f, s2 = 0.f;
  if (t < 128) {
    #pragma unroll
    for (int s = 0; s < 8; ++s) ctx += sCtx[s * 128 + t];
    s1 = ctx; s2 = ctx * ctx;
  }
  float mean = blockSum(s1, sRed) * (1.f / 128.f);
  float msq  = blockSum(s2, sRed) * (1.f / 128.f);
  if (t < 128) {
    float var = fmaxf(msq - mean * mean, 0.f);
    float r = rsqrtf(var + 1e-5f);
    out[(size_t)q * 128 + t] = (ctx - mean) * r * gamma[t] + beta[t];
  }
}

__global__ __launch_bounds__(256) void kl_finalize(const float* __restrict__ part,
                                                   float* __restrict__ out) {
  __shared__ float sRed[4];
  float v = 0.f;
  for (int i = threadIdx.x; i < NQ; i += 256) v += part[i];
  #pragma unroll
  for (int m = 32; m; m >>= 1) v += __shfl_xor(v, m);
  if ((threadIdx.x & 63) == 0) sRed[threadIdx.x >> 6] = v;
  __syncthreads();
  if (threadIdx.x == 0)
    out[(size_t)NQ * DD] = (sRed[0] + sRed[1] + sRed[2] + sRed[3]) * (1.f / ((float)NQ * (float)NK));
}

extern "C" void kernel_launch(void* const* d_in, const int* in_sizes, int n_in,
                              void* d_out, int out_size, void* d_ws, size_t ws_size,
                              hipStream_t stream) {
  const float* Q    = (const float*)d_in[0];
  const float* K    = (const float*)d_in[1];
  const float* V    = (const float*)d_in[2];
  const float* eps  = (const float*)d_in[3];
  const float* Wmu  = (const float*)d_in[4];
  const float* bmu  = (const float*)d_in[5];
  const float* Wlv  = (const float*)d_in[6];
  const float* blv  = (const float*)d_in[7];
  const float* Wp1  = (const float*)d_in[8];
  const float* bp1  = (const float*)d_in[9];
  const float* Wp2  = (const float*)d_in[10];
  const float* bp2  = (const float*)d_in[11];
  const float* gam  = (const float*)d_in[12];
  const float* bet  = (const float*)d_in[13];
  float* out = (float*)d_out;
  float* ws  = (float*)d_ws;                         // [0..2047] f32 KL partials
  bf16_t* wsW = (bf16_t*)((char*)d_ws + 8192);       // 16384 bf16 fragment-ready W

  prep_w<<<8, 256, 0, stream>>>(Wp1, wsW);
  fused_np_attn<<<NQ, 256, 0, stream>>>(Q, K, V, eps, Wmu, bmu, Wlv, blv,
                                        wsW, bp1, Wp2, bp2, gam, bet, out, ws);
  kl_finalize<<<1, 256, 0, stream>>>(ws, out);
}

// Round 3
// 463.933 us; speedup vs baseline: 1.3187x; 1.3187x over previous
//
#include <hip/hip_runtime.h>

#define NQ 2048
#define NK 512
#define DD 128

typedef __bf16 bf16_t;
typedef bf16_t bf16x4 __attribute__((ext_vector_type(4)));
typedef bf16_t bf16x8 __attribute__((ext_vector_type(8)));
typedef float  f32x4  __attribute__((ext_vector_type(4)));

// swizzled index into row-major [row][128] bf16 LDS tile (XOR byte-swizzle, G4/T2)
__device__ __forceinline__ int swz(int row, int d) {
  return row * 128 + (d ^ ((row & 7) << 3));
}

__device__ __forceinline__ float blockSum(float v, volatile float* sRed) {
  #pragma unroll
  for (int m = 32; m; m >>= 1) v += __shfl_xor(v, m);
  __syncthreads();                       // protect sRed from previous use
  if ((threadIdx.x & 63) == 0) sRed[threadIdx.x >> 6] = v;
  __syncthreads();
  return sRed[0] + sRed[1] + sRed[2] + sRed[3];
}

__device__ __forceinline__ float blockMax(float v, volatile float* sRed) {
  #pragma unroll
  for (int m = 32; m; m >>= 1) v = fmaxf(v, __shfl_xor(v, m));
  __syncthreads();
  if ((threadIdx.x & 63) == 0) sRed[threadIdx.x >> 6] = v;
  __syncthreads();
  return fmaxf(fmaxf(sRed[0], sRed[1]), fmaxf(sRed[2], sRed[3]));
}

// ---- prep: W_pr1 (128x128 f32) -> bf16, fragment-ready layout.
// idx = (et*4+kt)*64 + lane ; lane: rr=lane&15, rg=lane>>4
// frag j<4 : W[et*16+rr][kt*32+rg*4 + j]
// frag j>=4: W[et*16+rr][kt*32+rg*4 + 16 + j]
__global__ __launch_bounds__(256) void prep_w(const float* __restrict__ Wp1,
                                              bf16_t* __restrict__ wsW) {
  int idx = blockIdx.x * 256 + threadIdx.x;   // 0..2047
  int et = idx >> 8, kt = (idx >> 6) & 3, lane = idx & 63;
  int rr = lane & 15, rg = lane >> 4;
  int erow = et * 16 + rr;
  int dlo  = kt * 32 + rg * 4;
  bf16x8 v;
  #pragma unroll
  for (int j = 0; j < 4; ++j) v[j]     = (bf16_t)Wp1[erow * 128 + dlo + j];
  #pragma unroll
  for (int j = 0; j < 4; ++j) v[j + 4] = (bf16_t)Wp1[erow * 128 + dlo + 16 + j];
  *(bf16x8*)(&wsW[(size_t)idx * 8]) = v;
}

__global__ __launch_bounds__(256) void fused_np_attn(
    const float* __restrict__ Q,   const float* __restrict__ K,
    const float* __restrict__ V,   const float* __restrict__ eps,
    const float* __restrict__ Wmu, const float* __restrict__ bmu,
    const float* __restrict__ Wlv, const float* __restrict__ blv,
    const bf16_t* __restrict__ wsW, const float* __restrict__ bp1,
    const float* __restrict__ Wp2, const float* __restrict__ bp2,
    const float* __restrict__ gamma, const float* __restrict__ beta,
    float* __restrict__ out, float* __restrict__ klp)
{
  __shared__ __align__(16) bf16_t sK[64 * 128];   // K chunk [key][d] bf16, swizzled (16 KB); aliased as sCtx
  __shared__ float sB1[128], sW2[128], sWm2[128], sWl2[128];
  __shared__ float sKmu[NK], sKlv[NK], sMup[NK], sS[NK];
  __shared__ float sRed[4];

  const int q    = blockIdx.x;
  const int t    = threadIdx.x;
  const int lane = t & 63;
  const int wave = t >> 6;

  // ---- stage small vectors
  if (t < 128) {
    sB1[t]  = bp1[t];
    sW2[t]  = Wp2[t];
    sWm2[t] = Wmu[128 + t];
    sWl2[t] = Wlv[128 + t];
  }
  // ---- qmu, qlv = Q[q] . Wmu[:128], Wlv[:128]
  float pm = 0.f, pl = 0.f;
  if (t < 128) {
    float qv = Q[(size_t)q * 128 + t];
    pm = qv * Wmu[t];
    pl = qv * Wlv[t];
  }
  __syncthreads();   // small vectors ready; then reduce
  const float qmu = blockSum(pm, sRed);
  const float qlv = blockSum(pl, sRed);

  const float b_mu = bmu[0], b_lv = blv[0], b_p2 = bp2[0];

  // ================= chunked K processing =================
  const int rg = lane >> 4;    // 0..3 : k-group
  const int rr = lane & 15;    // 0..15: row-in-tile (A) / col e (B/D)
  const bf16x8* wsW8 = reinterpret_cast<const bf16x8*>(wsW);

  for (int chunk = 0; chunk < 8; ++chunk) {
    // ---- stage 64 keys x 128 d: thread t -> key=t>>2, d-range 32*(t&3)
    {
      int key  = t >> 2;
      int gkey = chunk * 64 + key;
      int d0   = (t & 3) * 32;
      const float* src = K + (((size_t)q * NK + gkey) * 128 + d0);
      float4 f[8];
      #pragma unroll
      for (int i = 0; i < 8; ++i) f[i] = *(const float4*)(src + i * 4);
      float kmu_p = 0.f, klv_p = 0.f;
      #pragma unroll
      for (int i = 0; i < 8; ++i) {
        int b = d0 + i * 4;
        kmu_p += f[i].x * sWm2[b] + f[i].y * sWm2[b + 1] + f[i].z * sWm2[b + 2] + f[i].w * sWm2[b + 3];
        klv_p += f[i].x * sWl2[b] + f[i].y * sWl2[b + 1] + f[i].z * sWl2[b + 2] + f[i].w * sWl2[b + 3];
      }
      #pragma unroll
      for (int i = 0; i < 4; ++i) {
        float4 a = f[2 * i], b2 = f[2 * i + 1];
        bf16x8 v = {(bf16_t)a.x,  (bf16_t)a.y,  (bf16_t)a.z,  (bf16_t)a.w,
                    (bf16_t)b2.x, (bf16_t)b2.y, (bf16_t)b2.z, (bf16_t)b2.w};
        *(bf16x8*)(&sK[swz(key, d0 + i * 8)]) = v;
      }
      kmu_p += __shfl_xor(kmu_p, 1); kmu_p += __shfl_xor(kmu_p, 2);
      klv_p += __shfl_xor(klv_p, 1); klv_p += __shfl_xor(klv_p, 2);
      if ((t & 3) == 0) { sKmu[gkey] = kmu_p; sKlv[gkey] = klv_p; }
    }
    __syncthreads();

    // ---- MFMA: wave handles keys [wave*16, wave*16+16); h = relu(K W1^T + b1); mup = h . W2
    f32x4 acc[8];
    #pragma unroll
    for (int et = 0; et < 8; ++et) acc[et] = 0;

    const int arow = wave * 16 + rr;
    #pragma unroll
    for (int kt = 0; kt < 4; ++kt) {
      int dlo = kt * 32 + rg * 4;
      bf16x4 alo = *(const bf16x4*)(&sK[swz(arow, dlo)]);
      bf16x4 ahi = *(const bf16x4*)(&sK[swz(arow, dlo + 16)]);
      bf16x8 a = {alo[0], alo[1], alo[2], alo[3], ahi[0], ahi[1], ahi[2], ahi[3]};
      #pragma unroll
      for (int et = 0; et < 8; ++et) {
        bf16x8 b = wsW8[(et * 4 + kt) * 64 + lane];   // L2-resident fragment
        acc[et] = __builtin_amdgcn_mfma_f32_16x16x32_bf16(a, b, acc[et], 0, 0, 0);
      }
    }
    // epilogue: relu + dot with W2, reduce over the 16 e-cols held across lanes
    float mup[4] = {0.f, 0.f, 0.f, 0.f};
    #pragma unroll
    for (int et = 0; et < 8; ++et) {
      int e = et * 16 + rr;
      float b1 = sB1[e], w2 = sW2[e];
      #pragma unroll
      for (int r = 0; r < 4; ++r) {
        float h = fmaxf(acc[et][r] + b1, 0.f);
        mup[r] += h * w2;
      }
    }
    #pragma unroll
    for (int r = 0; r < 4; ++r) {
      mup[r] += __shfl_xor(mup[r], 1);
      mup[r] += __shfl_xor(mup[r], 2);
      mup[r] += __shfl_xor(mup[r], 4);
      mup[r] += __shfl_xor(mup[r], 8);
    }
    if (rr == 0) {
      #pragma unroll
      for (int r = 0; r < 4; ++r)
        sMup[chunk * 64 + wave * 16 + rg * 4 + r] = mup[r] + b_p2 - 0.5f;
    }
    __syncthreads();   // sMup done; sK free for next chunk
  }

  // ================= posterior, KL, samples =================
  float klacc = 0.f, smax = -1e30f;
  float sval[2];
  #pragma unroll
  for (int i = 0; i < 2; ++i) {
    int k = t + i * 256;
    float kmu = sKmu[k], klv = sKlv[k], mupr = sMup[k];
    float mu0 = qmu + kmu + b_mu;
    float lv  = qlv + klv + b_lv;
    float sp  = expf(0.5f * lv);
    float sp2 = sp * sp;
    float mu  = mu0 - 0.5f * sp2;
    float dd  = mu - mupr;
    klacc += -0.5f * lv + 0.5f * (sp2 + dd * dd) - 0.5f;
    float s = expf(mu + sp * eps[(size_t)q * NK + k]);
    sval[i] = s;
    smax = fmaxf(smax, s);
  }
  float mx = blockMax(smax, sRed);
  float esum = 0.f, ev[2];
  #pragma unroll
  for (int i = 0; i < 2; ++i) { ev[i] = expf(sval[i] - mx); esum += ev[i]; }
  float tot = blockSum(esum, sRed);
  float inv = 1.f / tot;
  #pragma unroll
  for (int i = 0; i < 2; ++i) sS[t + i * 256] = ev[i] * inv;   // weights
  float klb = blockSum(klacc, sRed);   // also orders sS writes before phase 3
  if (t == 0) klp[q] = klb;

  // ================= context = weights . V, then LayerNorm =================
  float* sCtx = reinterpret_cast<float*>(sK);   // 8 x 128 f32 (sK dead)
  {
    int slot = t >> 5, l16 = t & 31;
    f32x4 acc = 0;
    const float4* V4 = reinterpret_cast<const float4*>(V + (size_t)q * NK * 128);
    for (int key = slot; key < NK; key += 8) {
      float w = sS[key];
      float4 v = V4[key * 32 + l16];
      acc.x += w * v.x; acc.y += w * v.y; acc.z += w * v.z; acc.w += w * v.w;
    }
    *(f32x4*)(&sCtx[slot * 128 + l16 * 4]) = acc;
  }
  __syncthreads();

  float ctx = 0.f, s1 = 0.f, s2 = 0.f;
  if (t < 128) {
    #pragma unroll
    for (int s = 0; s < 8; ++s) ctx += sCtx[s * 128 + t];
    s1 = ctx; s2 = ctx * ctx;
  }
  float mean = blockSum(s1, sRed) * (1.f / 128.f);
  float msq  = blockSum(s2, sRed) * (1.f / 128.f);
  if (t < 128) {
    float var = fmaxf(msq - mean * mean, 0.f);
    float r = rsqrtf(var + 1e-5f);
    out[(size_t)q * 128 + t] = (ctx - mean) * r * gamma[t] + beta[t];
  }
}

__global__ __launch_bounds__(256) void kl_finalize(const float* __restrict__ part,
                                                   float* __restrict__ out) {
  __shared__ float sRed[4];
  float v = 0.f;
  for (int i = threadIdx.x; i < NQ; i += 256) v += part[i];
  #pragma unroll
  for (int m = 32; m; m >>= 1) v += __shfl_xor(v, m);
  if ((threadIdx.x & 63) == 0) sRed[threadIdx.x >> 6] = v;
  __syncthreads();
  if (threadIdx.x == 0)
    out[(size_t)NQ * DD] = (sRed[0] + sRed[1] + sRed[2] + sRed[3]) * (1.f / ((float)NQ * (float)NK));
}

extern "C" void kernel_launch(void* const* d_in, const int* in_sizes, int n_in,
                              void* d_out, int out_size, void* d_ws, size_t ws_size,
                              hipStream_t stream) {
  const float* Q    = (const float*)d_in[0];
  const float* K    = (const float*)d_in[1];
  const float* V    = (const float*)d_in[2];
  const float* eps  = (const float*)d_in[3];
  const float* Wmu  = (const float*)d_in[4];
  const float* bmu  = (const float*)d_in[5];
  const float* Wlv  = (const float*)d_in[6];
  const float* blv  = (const float*)d_in[7];
  const float* Wp1  = (const float*)d_in[8];
  const float* bp1  = (const float*)d_in[9];
  const float* Wp2  = (const float*)d_in[10];
  const float* bp2  = (const float*)d_in[11];
  const float* gam  = (const float*)d_in[12];
  const float* bet  = (const float*)d_in[13];
  float* out = (float*)d_out;
  float* ws  = (float*)d_ws;                         // [0..2047] f32 KL partials
  bf16_t* wsW = (bf16_t*)((char*)d_ws + 8192);       // 16384 bf16 fragment-ready W

  prep_w<<<8, 256, 0, stream>>>(Wp1, wsW);
  fused_np_attn<<<NQ, 256, 0, stream>>>(Q, K, V, eps, Wmu, bmu, Wlv, blv,
                                        wsW, bp1, Wp2, bp2, gam, bet, out, ws);
  kl_finalize<<<1, 256, 0, stream>>>(ws, out);
}

// Round 4
// 246.022 us; speedup vs baseline: 2.4867x; 1.8857x over previous
//
#include <hip/hip_runtime.h>

#define NQ 2048
#define NK 512
#define DD 128

typedef __bf16 bf16_t;
typedef bf16_t bf16x4 __attribute__((ext_vector_type(4)));
typedef bf16_t bf16x8 __attribute__((ext_vector_type(8)));
typedef float  f32x4  __attribute__((ext_vector_type(4)));

// swizzled index into row-major [row][128] bf16 LDS tile (XOR byte-swizzle, G4/T2)
__device__ __forceinline__ int swz(int row, int d) {
  return row * 128 + (d ^ ((row & 7) << 3));
}

__device__ __forceinline__ float blockSum(float v, volatile float* sRed) {
  #pragma unroll
  for (int m = 32; m; m >>= 1) v += __shfl_xor(v, m);
  __syncthreads();
  if ((threadIdx.x & 63) == 0) sRed[threadIdx.x >> 6] = v;
  __syncthreads();
  return sRed[0] + sRed[1] + sRed[2] + sRed[3];
}

__device__ __forceinline__ float blockMax(float v, volatile float* sRed) {
  #pragma unroll
  for (int m = 32; m; m >>= 1) v = fmaxf(v, __shfl_xor(v, m));
  __syncthreads();
  if ((threadIdx.x & 63) == 0) sRed[threadIdx.x >> 6] = v;
  __syncthreads();
  return fmaxf(fmaxf(sRed[0], sRed[1]), fmaxf(sRed[2], sRed[3]));
}

// ---- prep: W_pr1 (128x128 f32) -> bf16, fragment-ready layout (verified R3).
__global__ __launch_bounds__(256) void prep_w(const float* __restrict__ Wp1,
                                              bf16_t* __restrict__ wsW) {
  int idx = blockIdx.x * 256 + threadIdx.x;   // 0..2047
  int et = idx >> 8, kt = (idx >> 6) & 3, lane = idx & 63;
  int rr = lane & 15, rg = lane >> 4;
  int erow = et * 16 + rr;
  int dlo  = kt * 32 + rg * 4;
  bf16x8 v;
  #pragma unroll
  for (int j = 0; j < 4; ++j) v[j]     = (bf16_t)Wp1[erow * 128 + dlo + j];
  #pragma unroll
  for (int j = 0; j < 4; ++j) v[j + 4] = (bf16_t)Wp1[erow * 128 + dlo + 16 + j];
  *(bf16x8*)(&wsW[(size_t)idx * 8]) = v;
}

// ==================== K-stream: prior MLP + kmu/klv dots ====================
// one block = one (q, 64-key chunk). grid 2048*8.
__global__ __launch_bounds__(256) void k_prior(
    const float* __restrict__ K,   const bf16_t* __restrict__ wsW,
    const float* __restrict__ Wmu, const float* __restrict__ Wlv,
    const float* __restrict__ bp1, const float* __restrict__ Wp2,
    const float* __restrict__ bp2,
    float* __restrict__ kmuG, float* __restrict__ klvG, float* __restrict__ mupG)
{
  __shared__ __align__(16) bf16_t sW[128 * 128];  // fragment-linear, 32 KB
  __shared__ __align__(16) bf16_t sK[64 * 128];   // swizzled, 16 KB
  __shared__ float sWm2[128], sWl2[128], sB1[128], sW2[128];

  const int bid  = blockIdx.x;
  const int q    = bid >> 3;
  const int kbase = (bid & 7) * 64;
  const int t    = threadIdx.x;
  const int lane = t & 63;
  const int wave = t >> 6;
  const int base = q * NK;

  if (t < 128) {
    sWm2[t] = Wmu[128 + t];
    sWl2[t] = Wlv[128 + t];
    sB1[t]  = bp1[t];
    sW2[t]  = Wp2[t];
  }
  // W copy: fragment-linear, coalesced b128
  {
    const int4* src = reinterpret_cast<const int4*>(wsW);
    int4* dst = reinterpret_cast<int4*>(sW);
    #pragma unroll
    for (int i = 0; i < 8; ++i) dst[t + 256 * i] = src[t + 256 * i];
  }
  // K chunk loads (issued before barrier; consumed after)
  const int key  = t >> 2;
  const int gkey = kbase + key;
  const int d0   = (t & 3) * 32;
  const float* src = K + (((size_t)base + gkey) * 128 + d0);
  float4 f[8];
  #pragma unroll
  for (int i = 0; i < 8; ++i) f[i] = *(const float4*)(src + i * 4);

  __syncthreads();   // sWm2/sWl2 ready

  float kmu_p = 0.f, klv_p = 0.f;
  #pragma unroll
  for (int i = 0; i < 8; ++i) {
    int b = d0 + i * 4;
    kmu_p += f[i].x * sWm2[b] + f[i].y * sWm2[b + 1] + f[i].z * sWm2[b + 2] + f[i].w * sWm2[b + 3];
    klv_p += f[i].x * sWl2[b] + f[i].y * sWl2[b + 1] + f[i].z * sWl2[b + 2] + f[i].w * sWl2[b + 3];
  }
  #pragma unroll
  for (int i = 0; i < 4; ++i) {
    float4 a = f[2 * i], b2 = f[2 * i + 1];
    bf16x8 v = {(bf16_t)a.x,  (bf16_t)a.y,  (bf16_t)a.z,  (bf16_t)a.w,
                (bf16_t)b2.x, (bf16_t)b2.y, (bf16_t)b2.z, (bf16_t)b2.w};
    *(bf16x8*)(&sK[swz(key, d0 + i * 8)]) = v;
  }
  kmu_p += __shfl_xor(kmu_p, 1); kmu_p += __shfl_xor(kmu_p, 2);
  klv_p += __shfl_xor(klv_p, 1); klv_p += __shfl_xor(klv_p, 2);
  if ((t & 3) == 0) { kmuG[base + gkey] = kmu_p; klvG[base + gkey] = klv_p; }

  __syncthreads();   // sK + sW ready

  // ---- MFMA: wave handles keys [wave*16, wave*16+16)
  const int rg = lane >> 4;
  const int rr = lane & 15;
  const bf16x8* sW8 = reinterpret_cast<const bf16x8*>(sW);

  f32x4 acc[8];
  #pragma unroll
  for (int et = 0; et < 8; ++et) acc[et] = 0;

  const int arow = wave * 16 + rr;
  #pragma unroll
  for (int kt = 0; kt < 4; ++kt) {
    int dlo = kt * 32 + rg * 4;
    bf16x4 alo = *(const bf16x4*)(&sK[swz(arow, dlo)]);
    bf16x4 ahi = *(const bf16x4*)(&sK[swz(arow, dlo + 16)]);
    bf16x8 a = {alo[0], alo[1], alo[2], alo[3], ahi[0], ahi[1], ahi[2], ahi[3]};
    #pragma unroll
    for (int et = 0; et < 8; ++et) {
      bf16x8 b = sW8[(et * 4 + kt) * 64 + lane];
      acc[et] = __builtin_amdgcn_mfma_f32_16x16x32_bf16(a, b, acc[et], 0, 0, 0);
    }
  }
  // epilogue: relu + dot with W2, reduce over 16 e-cols across lanes
  const float b_p2 = bp2[0];
  float mup[4] = {0.f, 0.f, 0.f, 0.f};
  #pragma unroll
  for (int et = 0; et < 8; ++et) {
    int e = et * 16 + rr;
    float b1 = sB1[e], w2 = sW2[e];
    #pragma unroll
    for (int r = 0; r < 4; ++r) {
      float h = fmaxf(acc[et][r] + b1, 0.f);
      mup[r] += h * w2;
    }
  }
  #pragma unroll
  for (int r = 0; r < 4; ++r) {
    mup[r] += __shfl_xor(mup[r], 1);
    mup[r] += __shfl_xor(mup[r], 2);
    mup[r] += __shfl_xor(mup[r], 4);
    mup[r] += __shfl_xor(mup[r], 8);
  }
  if (rr == 0) {
    #pragma unroll
    for (int r = 0; r < 4; ++r)
      mupG[base + kbase + wave * 16 + rg * 4 + r] = mup[r] + b_p2 - 0.5f;
  }
}

// ==================== posterior + softmax + KL + V-stream + LN ====================
// one block per q. grid 2048. small LDS -> full occupancy streaming.
__global__ __launch_bounds__(256) void k_ctx(
    const float* __restrict__ Q,   const float* __restrict__ V,
    const float* __restrict__ eps,
    const float* __restrict__ Wmu, const float* __restrict__ bmu,
    const float* __restrict__ Wlv, const float* __restrict__ blv,
    const float* __restrict__ kmuG, const float* __restrict__ klvG,
    const float* __restrict__ mupG,
    const float* __restrict__ gamma, const float* __restrict__ beta,
    float* __restrict__ out, float* __restrict__ klp)
{
  __shared__ float sS[NK];          // weights
  __shared__ float sCtx[8 * 128];   // per-slot partial context
  __shared__ float sRed[4];

  const int q = blockIdx.x;
  const int t = threadIdx.x;
  const int base = q * NK;

  // qmu, qlv
  float pm = 0.f, pl = 0.f;
  if (t < 128) {
    float qv = Q[(size_t)q * 128 + t];
    pm = qv * Wmu[t];
    pl = qv * Wlv[t];
  }
  const float qmu = blockSum(pm, sRed);
  const float qlv = blockSum(pl, sRed);
  const float b_mu = bmu[0], b_lv = blv[0];

  // posterior + KL + samples (2 keys/thread)
  float klacc = 0.f, smax = -1e30f;
  float sval[2];
  #pragma unroll
  for (int i = 0; i < 2; ++i) {
    int k = t + i * 256;
    float kmu = kmuG[base + k], klv = klvG[base + k], mupr = mupG[base + k];
    float mu0 = qmu + kmu + b_mu;
    float lv  = qlv + klv + b_lv;
    float sp  = expf(0.5f * lv);
    float sp2 = sp * sp;
    float mu  = mu0 - 0.5f * sp2;
    float dd  = mu - mupr;
    klacc += -0.5f * lv + 0.5f * (sp2 + dd * dd) - 0.5f;
    float s = expf(mu + sp * eps[(size_t)base + k]);
    sval[i] = s;
    smax = fmaxf(smax, s);
  }
  float mx = blockMax(smax, sRed);
  float esum = 0.f, ev[2];
  #pragma unroll
  for (int i = 0; i < 2; ++i) { ev[i] = expf(sval[i] - mx); esum += ev[i]; }
  float tot = blockSum(esum, sRed);
  float inv = 1.f / tot;
  #pragma unroll
  for (int i = 0; i < 2; ++i) sS[t + i * 256] = ev[i] * inv;
  float klb = blockSum(klacc, sRed);   // barrier inside also orders sS before V loop
  if (t == 0) klp[q] = klb;

  // V-stream: slot/key decomposition, 64 iters of independent float4 loads
  {
    const int slot = t >> 5, l16 = t & 31;
    f32x4 acc = 0;
    const float4* V4 = reinterpret_cast<const float4*>(V + (size_t)base * 128);
    #pragma unroll 4
    for (int key = slot; key < NK; key += 8) {
      float w = sS[key];
      float4 v = V4[key * 32 + l16];
      acc.x += w * v.x; acc.y += w * v.y; acc.z += w * v.z; acc.w += w * v.w;
    }
    *(f32x4*)(&sCtx[slot * 128 + l16 * 4]) = acc;
  }
  __syncthreads();

  float ctx = 0.f, s1 = 0.f, s2 = 0.f;
  if (t < 128) {
    #pragma unroll
    for (int s = 0; s < 8; ++s) ctx += sCtx[s * 128 + t];
    s1 = ctx; s2 = ctx * ctx;
  }
  float mean = blockSum(s1, sRed) * (1.f / 128.f);
  float msq  = blockSum(s2, sRed) * (1.f / 128.f);
  if (t < 128) {
    float var = fmaxf(msq - mean * mean, 0.f);
    float r = rsqrtf(var + 1e-5f);
    out[(size_t)q * 128 + t] = (ctx - mean) * r * gamma[t] + beta[t];
  }
}

__global__ __launch_bounds__(256) void kl_finalize(const float* __restrict__ part,
                                                   float* __restrict__ out) {
  __shared__ float sRed[4];
  float v = 0.f;
  for (int i = threadIdx.x; i < NQ; i += 256) v += part[i];
  #pragma unroll
  for (int m = 32; m; m >>= 1) v += __shfl_xor(v, m);
  if ((threadIdx.x & 63) == 0) sRed[threadIdx.x >> 6] = v;
  __syncthreads();
  if (threadIdx.x == 0)
    out[(size_t)NQ * DD] = (sRed[0] + sRed[1] + sRed[2] + sRed[3]) * (1.f / ((float)NQ * (float)NK));
}

extern "C" void kernel_launch(void* const* d_in, const int* in_sizes, int n_in,
                              void* d_out, int out_size, void* d_ws, size_t ws_size,
                              hipStream_t stream) {
  const float* Q    = (const float*)d_in[0];
  const float* K    = (const float*)d_in[1];
  const float* V    = (const float*)d_in[2];
  const float* eps  = (const float*)d_in[3];
  const float* Wmu  = (const float*)d_in[4];
  const float* bmu  = (const float*)d_in[5];
  const float* Wlv  = (const float*)d_in[6];
  const float* blv  = (const float*)d_in[7];
  const float* Wp1  = (const float*)d_in[8];
  const float* bp1  = (const float*)d_in[9];
  const float* Wp2  = (const float*)d_in[10];
  const float* bp2  = (const float*)d_in[11];
  const float* gam  = (const float*)d_in[12];
  const float* bet  = (const float*)d_in[13];
  float* out = (float*)d_out;

  // ws layout: [0,8K): 2048 f32 KL partials | [8K,40K): wsW bf16 fragments |
  // [40K, 40K+12MB): kmuG, klvG, mupG (each NQ*NK f32)
  float*  klp  = (float*)d_ws;
  bf16_t* wsW  = (bf16_t*)((char*)d_ws + 8192);
  float*  kmuG = (float*)((char*)d_ws + 40960);
  float*  klvG = kmuG + (size_t)NQ * NK;
  float*  mupG = klvG + (size_t)NQ * NK;

  prep_w<<<8, 256, 0, stream>>>(Wp1, wsW);
  k_prior<<<NQ * 8, 256, 0, stream>>>(K, wsW, Wmu, Wlv, bp1, Wp2, bp2,
                                      kmuG, klvG, mupG);
  k_ctx<<<NQ, 256, 0, stream>>>(Q, V, eps, Wmu, bmu, Wlv, blv,
                                kmuG, klvG, mupG, gam, bet, out, klp);
  kl_finalize<<<1, 256, 0, stream>>>(klp, out);
}